// Round 1
// baseline (10494.321 us; speedup 1.0000x reference)
//
#include <hip/hip_runtime.h>
#include <hip/hip_bf16.h>
#include <stdint.h>

typedef unsigned short ushort_t;
typedef __bf16 bf16x8 __attribute__((ext_vector_type(8)));
typedef float f32x4 __attribute__((ext_vector_type(4)));

#define T_STEPS 196

// ---- workspace layout (bytes) ----
#define O_WPACK 0u
#define SZ_WPACK (2u*2048u*1024u*2u)            // packed [Wih|Whh] bf16, 8 MB
#define O_WFC   (O_WPACK + SZ_WPACK)
#define SZ_WFC  (5120u*512u*2u)                 // W_fc bf16 padded to 5120 rows
#define O_BIAS  (O_WFC + SZ_WFC)
#define SZ_BIAS (2u*2048u*4u)                   // b_ih + b_hh, f32
#define O_SEQT  (O_BIAS + SZ_BIAS)
#define SZ_SEQT (196u*64u*512u*2u)              // x transposed -> [t][b][i] bf16
#define O_H     (O_SEQT + SZ_SEQT)
#define SZ_H    (2u*196u*64u*512u*2u)           // h_all[layer][t][b][h] bf16
#define O_CTR   (O_H + SZ_H)                    // 8 group counters (+pad)

// scan LDS: weights [64][1032] + in [16][520] + gates [64][16] f32
#define SCAN_LDS_BYTES (64*1032*2 + 16*520*2 + 64*16*4)   // 152,832 B

__device__ __forceinline__ ushort_t f2bf(float v) {
  __hip_bfloat16 h = __float2bfloat16(v);
  return __builtin_bit_cast(ushort_t, h);
}

__device__ __forceinline__ void spin_ge(unsigned int* p, unsigned int tgt) {
  int n = 0;
  while (__hip_atomic_load(p, __ATOMIC_ACQUIRE, __HIP_MEMORY_SCOPE_AGENT) < tgt) {
    __builtin_amdgcn_s_sleep(2);
    if (++n > (1 << 24)) break;   // safety: never hang the harness
  }
}

// ---------------- prep: cast/pack weights, biases, zero counters ----------------
__global__ __launch_bounds__(256) void prep_pack(
    const float* __restrict__ Wih0, const float* __restrict__ Whh0,
    const float* __restrict__ bih0, const float* __restrict__ bhh0,
    const float* __restrict__ Wih1, const float* __restrict__ Whh1,
    const float* __restrict__ bih1, const float* __restrict__ bhh1,
    const float* __restrict__ Wfc,
    ushort_t* __restrict__ wpack, ushort_t* __restrict__ wfcp,
    float* __restrict__ bias, unsigned int* __restrict__ ctr)
{
  const size_t NW_ = 2u*2048u*1024u;   // 4,194,304
  const size_t NF  = 5120u*512u;       // 2,621,440
  const size_t NB  = 2u*2048u;
  const size_t TOT = NW_ + NF + NB + 16u;
  for (size_t idx = (size_t)blockIdx.x*256 + threadIdx.x; idx < TOT;
       idx += (size_t)gridDim.x*256) {
    if (idx < NW_) {
      int l   = (int)(idx >> 21);
      int rem = (int)(idx & ((1u<<21)-1));
      int r = rem >> 10, k = rem & 1023;
      const float* src = (k < 512) ? (l ? Wih1 : Wih0) : (l ? Whh1 : Whh0);
      wpack[idx] = f2bf(src[(size_t)r*512 + (k & 511)]);
    } else if (idx < NW_ + NF) {
      size_t i2 = idx - NW_;
      int n = (int)(i2 >> 9), k = (int)(i2 & 511);
      wfcp[i2] = (n < 5000) ? f2bf(Wfc[(size_t)n*512 + k]) : (ushort_t)0;
    } else if (idx < NW_ + NF + NB) {
      size_t i2 = idx - NW_ - NF;
      int l = (int)(i2 >> 11), r = (int)(i2 & 2047);
      bias[i2] = l ? (bih1[r] + bhh1[r]) : (bih0[r] + bhh0[r]);
    } else {
      ctr[idx - NW_ - NF - NB] = 0u;
    }
  }
}

// ---------------- prep: x (64,512,196) f32 -> seqT [196][64][512] bf16 ----------------
__global__ __launch_bounds__(256) void prep_seq(const float* __restrict__ x,
                                                ushort_t* __restrict__ seqT)
{
  __shared__ float tile[64 * 197];
  int b = blockIdx.x >> 3, ic = blockIdx.x & 7;
  const float* src = x + ((size_t)b*512 + ic*64) * 196;
  for (int it = 0; it < 49; ++it) {              // 64*196 = 49*256
    int idx = threadIdx.x + it*256;
    int row = idx / 196, t = idx % 196;
    tile[row*197 + t] = src[idx];
  }
  __syncthreads();
  for (int it = 0; it < 49; ++it) {
    int idx = threadIdx.x + it*256;
    int t = idx >> 6, ii = idx & 63;
    seqT[(size_t)t*(64*512) + (size_t)b*512 + ic*64 + ii] = f2bf(tile[ii*197 + t]);
  }
}

// ---------------- fused 2-layer LSTM scan (weight-stationary, pipelined) ----------------
// grid = 256 wgs: layer(2) x bslice(4, 16 batch each) x gslice(32, 16 h-dims each)
__global__ __launch_bounds__(256, 1) void lstm_scan(
    const ushort_t* __restrict__ wpack, const float* __restrict__ bias,
    const ushort_t* __restrict__ seqT, ushort_t* __restrict__ h_all,
    unsigned int* ctr)
{
  extern __shared__ char smem[];
  ushort_t* w_s  = (ushort_t*)smem;                          // [64][1032] bf16 bits
  ushort_t* in_s = (ushort_t*)(smem + 64*1032*2);            // [16][520]
  float*    g_s  = (float*)(smem + 64*1032*2 + 16*520*2);    // [64][16]

  const int wg = blockIdx.x;
  const int layer = wg >> 7;
  const int bs = (wg >> 5) & 3;
  const int gs = wg & 31;
  const int tid = threadIdx.x;
  const int wv = tid >> 6;
  const int lane = tid & 63;
  const int lr = lane & 15;
  const int lg = lane >> 4;

  // load my weight slice: rows r = 512*q + gs*16 + j  (q = gate, j = h-dim)
  const ushort_t* wbase = wpack + (size_t)layer * (2048*1024);
  #pragma unroll 4
  for (int it = 0; it < 32; ++it) {
    int ch = tid + it*256;            // 64 rows * 128 chunks(16B)
    int row = ch >> 7, kc = ch & 127;
    int q = row >> 4, j = row & 15;
    const ushort_t* g = wbase + (size_t)(512*q + gs*16 + j)*1024 + kc*8;
    *(uint4*)&w_s[row*1032 + kc*8] = *(const uint4*)g;
  }

  unsigned int* ctr_self = ctr + (layer*4 + bs);
  unsigned int* ctr_dep  = ctr + bs;          // layer 0's counter for this bslice

  const int b_loc = tid >> 4;   // batch within slice
  const int hd    = tid & 15;   // h-dim within slice
  const float b_i = bias[layer*2048 +    0 + gs*16 + hd];
  const float b_f = bias[layer*2048 +  512 + gs*16 + hd];
  const float b_g = bias[layer*2048 + 1024 + gs*16 + hd];
  const float b_o = bias[layer*2048 + 1536 + gs*16 + hd];

  const ushort_t* xbase = (layer == 0) ? seqT : h_all;   // layer1 input = h_all[0]
  ushort_t* hout = h_all + (size_t)layer * (196*64*512);

  float c_reg = 0.f;
  const int wrow = (wv*16 + lr) * 1032;
  const int brow = lr * 520;
  const int koff = lg * 8;

  for (int t = 0; t < T_STEPS; ++t) {
    if (layer == 1) spin_ge(ctr_dep, 32u*(unsigned)(t+1));   // need h0[t]
    if (t > 0)      spin_ge(ctr_self, 32u*(unsigned)t);      // need peers' h[t-1]

    {  // stage x_t (16x512 bf16)
      const ushort_t* xsrc = xbase + ((size_t)t*64 + bs*16) * 512;
      #pragma unroll
      for (int it = 0; it < 4; ++it) {
        int ch = tid + it*256;
        int row = ch >> 6, kc = ch & 63;
        *(uint4*)&in_s[row*520 + kc*8] = *(const uint4*)&xsrc[row*512 + kc*8];
      }
    }
    __syncthreads();

    f32x4 acc = {0.f, 0.f, 0.f, 0.f};
    #pragma unroll
    for (int ks = 0; ks < 16; ++ks) {                  // W_ih * x_t
      bf16x8 a = *(const bf16x8*)&w_s[wrow + ks*32 + koff];
      bf16x8 bb = *(const bf16x8*)&in_s[brow + ks*32 + koff];
      acc = __builtin_amdgcn_mfma_f32_16x16x32_bf16(a, bb, acc, 0, 0, 0);
    }
    __syncthreads();

    if (t > 0) {   // h_{t-1} pass (h_0 = 0 -> skipped)
      const ushort_t* hsrc = hout + ((size_t)(t-1)*64 + bs*16) * 512;
      #pragma unroll
      for (int it = 0; it < 4; ++it) {
        int ch = tid + it*256;
        int row = ch >> 6, kc = ch & 63;
        *(uint4*)&in_s[row*520 + kc*8] = *(const uint4*)&hsrc[row*512 + kc*8];
      }
      __syncthreads();
      #pragma unroll
      for (int ks = 0; ks < 16; ++ks) {                // W_hh * h_{t-1}
        bf16x8 a = *(const bf16x8*)&w_s[wrow + 512 + ks*32 + koff];
        bf16x8 bb = *(const bf16x8*)&in_s[brow + ks*32 + koff];
        acc = __builtin_amdgcn_mfma_f32_16x16x32_bf16(a, bb, acc, 0, 0, 0);
      }
    }

    // D layout: row = lg*4 + reg (gate-local h-dim), col = lr (batch)
    #pragma unroll
    for (int j2 = 0; j2 < 4; ++j2)
      g_s[(wv*16 + lg*4 + j2)*16 + lr] = acc[j2];
    __syncthreads();

    // elementwise cell update: one (hd, b) pair per thread
    float gi = g_s[(  0 + hd)*16 + b_loc] + b_i;
    float gf = g_s[( 16 + hd)*16 + b_loc] + b_f;
    float gg = g_s[( 32 + hd)*16 + b_loc] + b_g;
    float go = g_s[( 48 + hd)*16 + b_loc] + b_o;
    float si = 1.f/(1.f + __expf(-gi));
    float sf = 1.f/(1.f + __expf(-gf));
    float tg = tanhf(gg);
    float so = 1.f/(1.f + __expf(-go));
    c_reg = sf*c_reg + si*tg;
    float hv = so * tanhf(c_reg);
    hout[((size_t)t*64 + bs*16 + b_loc)*512 + gs*16 + hd] = f2bf(hv);

    __threadfence();           // agent-scope release of h writes
    __syncthreads();
    if (tid == 0)
      __hip_atomic_fetch_add(ctr_self, 1u, __ATOMIC_RELEASE, __HIP_MEMORY_SCOPE_AGENT);
  }
}

// ---------------- FC: out[b][t][v] = h1[t*64+b] . wfc[v] + bfc[v] ----------------
__global__ __launch_bounds__(256, 2) void fc_gemm(
    const ushort_t* __restrict__ h1,    // [12544][512] bf16
    const ushort_t* __restrict__ wfc,   // [5120][512] bf16 (padded)
    const float* __restrict__ bfc,      // [5000]
    float* __restrict__ out)            // [64][196][5000]
{
  __shared__ ushort_t As[128*32];
  __shared__ ushort_t Bs[128*32];
  const int tid = threadIdx.x;
  const int wvid = tid >> 6, lane = tid & 63;
  const int lr = lane & 15, lg = lane >> 4;
  const int wr = wvid >> 1, wc = wvid & 1;
  const int m0 = blockIdx.x * 128, n0 = blockIdx.y * 128;

  f32x4 acc[4][4];
  #pragma unroll
  for (int i = 0; i < 4; ++i)
    #pragma unroll
    for (int j = 0; j < 4; ++j)
      acc[i][j] = (f32x4){0.f, 0.f, 0.f, 0.f};

  for (int kt = 0; kt < 16; ++kt) {
    #pragma unroll
    for (int c = 0; c < 2; ++c) {
      int chb = wvid*128 + c*64;
      int ch = chb + lane;
      int m = ch >> 2, kh = ch & 3;
      const ushort_t* ga = h1  + (size_t)(m0 + m)*512 + kt*32 + kh*8;
      __builtin_amdgcn_global_load_lds(
          (const __attribute__((address_space(1))) void*)ga,
          (__attribute__((address_space(3))) void*)&As[chb*8], 16, 0, 0);
      const ushort_t* gb = wfc + (size_t)(n0 + m)*512 + kt*32 + kh*8;
      __builtin_amdgcn_global_load_lds(
          (const __attribute__((address_space(1))) void*)gb,
          (__attribute__((address_space(3))) void*)&Bs[chb*8], 16, 0, 0);
    }
    asm volatile("s_waitcnt vmcnt(0)" ::: "memory");
    __syncthreads();

    bf16x8 af[4], bf_[4];
    #pragma unroll
    for (int i = 0; i < 4; ++i)
      af[i] = *(const bf16x8*)&As[(wr*64 + i*16 + lr)*32 + lg*8];
    #pragma unroll
    for (int j = 0; j < 4; ++j)
      bf_[j] = *(const bf16x8*)&Bs[(wc*64 + j*16 + lr)*32 + lg*8];
    #pragma unroll
    for (int i = 0; i < 4; ++i)
      #pragma unroll
      for (int j = 0; j < 4; ++j)
        acc[i][j] = __builtin_amdgcn_mfma_f32_16x16x32_bf16(af[i], bf_[j], acc[i][j], 0, 0, 0);
    __syncthreads();
  }

  #pragma unroll
  for (int j = 0; j < 4; ++j) {
    int coln = n0 + wc*64 + j*16 + lr;
    if (coln >= 5000) continue;
    float bb = bfc[coln];
    #pragma unroll
    for (int i = 0; i < 4; ++i) {
      #pragma unroll
      for (int jj = 0; jj < 4; ++jj) {
        int rowm = m0 + wr*64 + i*16 + lg*4 + jj;
        int tt = rowm >> 6, b2 = rowm & 63;
        out[(size_t)b2*980000 + (size_t)tt*5000 + coln] = acc[i][j][jj] + bb;
      }
    }
  }
}

extern "C" void kernel_launch(void* const* d_in, const int* in_sizes, int n_in,
                              void* d_out, int out_size, void* d_ws, size_t ws_size,
                              hipStream_t stream) {
  const float* x    = (const float*)d_in[0];
  const float* Wih0 = (const float*)d_in[1];
  const float* Whh0 = (const float*)d_in[2];
  const float* bih0 = (const float*)d_in[3];
  const float* bhh0 = (const float*)d_in[4];
  const float* Wih1 = (const float*)d_in[5];
  const float* Whh1 = (const float*)d_in[6];
  const float* bih1 = (const float*)d_in[7];
  const float* bhh1 = (const float*)d_in[8];
  const float* Wfc  = (const float*)d_in[9];
  const float* bfc  = (const float*)d_in[10];

  char* ws = (char*)d_ws;
  ushort_t* wpack = (ushort_t*)(ws + O_WPACK);
  ushort_t* wfcp  = (ushort_t*)(ws + O_WFC);
  float*    bias  = (float*)(ws + O_BIAS);
  ushort_t* seqT  = (ushort_t*)(ws + O_SEQT);
  ushort_t* h_all = (ushort_t*)(ws + O_H);
  unsigned int* ctr = (unsigned int*)(ws + O_CTR);

  hipFuncSetAttribute((const void*)lstm_scan,
                      hipFuncAttributeMaxDynamicSharedMemorySize, SCAN_LDS_BYTES);

  prep_pack<<<4096, 256, 0, stream>>>(Wih0, Whh0, bih0, bhh0,
                                      Wih1, Whh1, bih1, bhh1,
                                      Wfc, wpack, wfcp, bias, ctr);
  prep_seq<<<512, 256, 0, stream>>>(x, seqT);
  lstm_scan<<<256, 256, SCAN_LDS_BYTES, stream>>>(wpack, bias, seqT, h_all, ctr);
  dim3 fcg(98, 40);
  fc_gemm<<<fcg, 256, 0, stream>>>(h_all + (size_t)196*64*512, wfcp, bfc,
                                   (float*)d_out);
}

// Round 2
// 1491.433 us; speedup vs baseline: 7.0364x; 7.0364x over previous
//
#include <hip/hip_runtime.h>
#include <hip/hip_bf16.h>
#include <stdint.h>

typedef unsigned short ushort_t;
typedef __bf16 bf16x8 __attribute__((ext_vector_type(8)));
typedef float f32x4 __attribute__((ext_vector_type(4)));

#define T_STEPS 196

// ---- workspace layout (bytes) ----
#define O_WPACK 0u
#define SZ_WPACK (2u*2048u*1024u*2u)            // packed [Wih|Whh] bf16, 8 MB
#define O_WFC   (O_WPACK + SZ_WPACK)
#define SZ_WFC  (5120u*512u*2u)                 // W_fc bf16 padded to 5120 rows
#define O_BIAS  (O_WFC + SZ_WFC)
#define SZ_BIAS (2u*2048u*4u)                   // b_ih + b_hh, f32
#define O_SEQT  (O_BIAS + SZ_BIAS)
#define SZ_SEQT (196u*64u*512u*2u)              // x transposed -> [t][b][i] bf16
#define O_H     (O_SEQT + SZ_SEQT)
#define SZ_H    (2u*196u*64u*512u*2u)           // h_all[layer][t][b][h] bf16
#define O_FLG   (O_H + SZ_H)                    // flags[8 groups][32 wgs], u32
#define N_FLG   256u

// scan LDS: weights [64][1032] + in [16][520] + gates [64][16] f32
#define SCAN_LDS_BYTES (64*1032*2 + 16*520*2 + 64*16*4)   // 152,832 B

__device__ __forceinline__ ushort_t f2bf(float v) {
  __hip_bfloat16 h = __float2bfloat16(v);
  return __builtin_bit_cast(ushort_t, h);
}

// Poll 32 per-producer flags (lane l watches flag l&31) until all >= tgt.
// RELAXED agent-scope loads: coherent (bypass stale L2) but NO bulk
// buffer_inv per iteration (the round-1 killer).
__device__ __forceinline__ void poll32(unsigned int* f, unsigned int tgt, int lane) {
  int n = 0;
  for (;;) {
    unsigned int v = __hip_atomic_load(&f[lane & 31], __ATOMIC_RELAXED,
                                       __HIP_MEMORY_SCOPE_AGENT);
    if (__all((int)(v >= tgt))) break;
    if (++n > (1 << 22)) break;   // safety: never hang the harness
  }
  asm volatile("" ::: "memory");  // keep subsequent loads after the poll
}

// ---------------- prep: cast/pack weights, biases, zero flags ----------------
__global__ __launch_bounds__(256) void prep_pack(
    const float* __restrict__ Wih0, const float* __restrict__ Whh0,
    const float* __restrict__ bih0, const float* __restrict__ bhh0,
    const float* __restrict__ Wih1, const float* __restrict__ Whh1,
    const float* __restrict__ bih1, const float* __restrict__ bhh1,
    const float* __restrict__ Wfc,
    ushort_t* __restrict__ wpack, ushort_t* __restrict__ wfcp,
    float* __restrict__ bias, unsigned int* __restrict__ flg)
{
  const size_t NW_ = 2u*2048u*1024u;   // 4,194,304
  const size_t NF  = 5120u*512u;       // 2,621,440
  const size_t NB  = 2u*2048u;
  const size_t TOT = NW_ + NF + NB + N_FLG;
  for (size_t idx = (size_t)blockIdx.x*256 + threadIdx.x; idx < TOT;
       idx += (size_t)gridDim.x*256) {
    if (idx < NW_) {
      int l   = (int)(idx >> 21);
      int rem = (int)(idx & ((1u<<21)-1));
      int r = rem >> 10, k = rem & 1023;
      const float* src = (k < 512) ? (l ? Wih1 : Wih0) : (l ? Whh1 : Whh0);
      wpack[idx] = f2bf(src[(size_t)r*512 + (k & 511)]);
    } else if (idx < NW_ + NF) {
      size_t i2 = idx - NW_;
      int n = (int)(i2 >> 9), k = (int)(i2 & 511);
      wfcp[i2] = (n < 5000) ? f2bf(Wfc[(size_t)n*512 + k]) : (ushort_t)0;
    } else if (idx < NW_ + NF + NB) {
      size_t i2 = idx - NW_ - NF;
      int l = (int)(i2 >> 11), r = (int)(i2 & 2047);
      bias[i2] = l ? (bih1[r] + bhh1[r]) : (bih0[r] + bhh0[r]);
    } else {
      flg[idx - NW_ - NF - NB] = 0u;
    }
  }
}

// ---------------- prep: x (64,512,196) f32 -> seqT [196][64][512] bf16 ----------------
__global__ __launch_bounds__(256) void prep_seq(const float* __restrict__ x,
                                                ushort_t* __restrict__ seqT)
{
  __shared__ float tile[64 * 197];
  int b = blockIdx.x >> 3, ic = blockIdx.x & 7;
  const float* src = x + ((size_t)b*512 + ic*64) * 196;
  for (int it = 0; it < 49; ++it) {              // 64*196 = 49*256
    int idx = threadIdx.x + it*256;
    int row = idx / 196, t = idx % 196;
    tile[row*197 + t] = src[idx];
  }
  __syncthreads();
  for (int it = 0; it < 49; ++it) {
    int idx = threadIdx.x + it*256;
    int t = idx >> 6, ii = idx & 63;
    seqT[(size_t)t*(64*512) + (size_t)b*512 + ic*64 + ii] = f2bf(tile[ii*197 + t]);
  }
}

// ---------------- fused 2-layer LSTM scan (weight-stationary, pipelined) ----------------
// grid = 256 wgs: layer(2) x bslice(4, 16 batch each) x gslice(32, 16 h-dims each)
// Sync protocol: per-producer flag words, relaxed agent-scope atomics only.
// NO acquire/release fences (they compile to bulk L2 inv/wb on gfx950).
__global__ __launch_bounds__(256, 1) void lstm_scan(
    const ushort_t* __restrict__ wpack, const float* __restrict__ bias,
    const ushort_t* __restrict__ seqT, ushort_t* __restrict__ h_all,
    unsigned int* flags)
{
  extern __shared__ char smem[];
  ushort_t* w_s  = (ushort_t*)smem;                          // [64][1032] bf16 bits
  ushort_t* in_s = (ushort_t*)(smem + 64*1032*2);            // [16][520]
  float*    g_s  = (float*)(smem + 64*1032*2 + 16*520*2);    // [64][16]

  const int wg = blockIdx.x;
  const int layer = wg >> 7;
  const int bs = (wg >> 5) & 3;
  const int gs = wg & 31;
  const int tid = threadIdx.x;
  const int wv = tid >> 6;
  const int lane = tid & 63;
  const int lr = lane & 15;
  const int lg = lane >> 4;

  // load my weight slice: rows r = 512*q + gs*16 + j  (q = gate, j = h-dim)
  const ushort_t* wbase = wpack + (size_t)layer * (2048*1024);
  #pragma unroll 4
  for (int it = 0; it < 32; ++it) {
    int ch = tid + it*256;            // 64 rows * 128 chunks(16B)
    int row = ch >> 7, kc = ch & 127;
    int q = row >> 4, j = row & 15;
    const ushort_t* g = wbase + (size_t)(512*q + gs*16 + j)*1024 + kc*8;
    *(uint4*)&w_s[row*1032 + kc*8] = *(const uint4*)g;
  }

  unsigned int* flg_self = flags + (layer*4 + bs)*32;
  unsigned int* flg_dep  = flags + bs*32;          // layer-0 group, same bslice

  const int b_loc = tid >> 4;   // batch within slice
  const int hd    = tid & 15;   // h-dim within slice
  const float b_i = bias[layer*2048 +    0 + gs*16 + hd];
  const float b_f = bias[layer*2048 +  512 + gs*16 + hd];
  const float b_g = bias[layer*2048 + 1024 + gs*16 + hd];
  const float b_o = bias[layer*2048 + 1536 + gs*16 + hd];

  ushort_t* hout = h_all + (size_t)layer * (196*64*512);
  const ushort_t* hdep = h_all;                    // layer-0 output stream

  float c_reg = 0.f;
  const int wrow = (wv*16 + lr) * 1032;
  const int brow = lr * 520;
  const int koff = lg * 8;

  for (int t = 0; t < T_STEPS; ++t) {
    // ---- input part: x_t = seqT[t] (layer 0) or h0[t] (layer 1) ----
    if (layer == 1) {
      if (wv == 0) poll32(flg_dep, (unsigned)(t + 1), lane);
      __syncthreads();
      const ushort_t* xsrc = hdep + ((size_t)t*64 + bs*16) * 512;
      #pragma unroll
      for (int it = 0; it < 8; ++it) {              // 2048 x 8B coherent loads
        int ch = tid + it*256;
        int row = ch >> 7, kc = ch & 127;
        unsigned long long v = __hip_atomic_load(
            (unsigned long long*)&xsrc[row*512 + kc*4],
            __ATOMIC_RELAXED, __HIP_MEMORY_SCOPE_AGENT);
        *(unsigned long long*)&in_s[row*520 + kc*4] = v;
      }
    } else {
      const ushort_t* xsrc = seqT + ((size_t)t*64 + bs*16) * 512;
      #pragma unroll
      for (int it = 0; it < 4; ++it) {              // plain 16B loads (static input)
        int ch = tid + it*256;
        int row = ch >> 6, kc = ch & 63;
        *(uint4*)&in_s[row*520 + kc*8] = *(const uint4*)&xsrc[row*512 + kc*8];
      }
    }
    __syncthreads();

    f32x4 acc = {0.f, 0.f, 0.f, 0.f};
    #pragma unroll
    for (int ks = 0; ks < 16; ++ks) {                  // W_ih * x_t
      bf16x8 a = *(const bf16x8*)&w_s[wrow + ks*32 + koff];
      bf16x8 bb = *(const bf16x8*)&in_s[brow + ks*32 + koff];
      acc = __builtin_amdgcn_mfma_f32_16x16x32_bf16(a, bb, acc, 0, 0, 0);
    }

    if (t > 0) {   // recurrent part (h_0 = 0 -> skipped at t=0)
      if (wv == 0) poll32(flg_self, (unsigned)t, lane);
      __syncthreads();                               // xMFMA done; in_s reusable
      const ushort_t* hsrc = hout + ((size_t)(t-1)*64 + bs*16) * 512;
      #pragma unroll
      for (int it = 0; it < 8; ++it) {               // coherent 8B loads
        int ch = tid + it*256;
        int row = ch >> 7, kc = ch & 127;
        unsigned long long v = __hip_atomic_load(
            (unsigned long long*)&hsrc[row*512 + kc*4],
            __ATOMIC_RELAXED, __HIP_MEMORY_SCOPE_AGENT);
        *(unsigned long long*)&in_s[row*520 + kc*4] = v;
      }
      __syncthreads();
      #pragma unroll
      for (int ks = 0; ks < 16; ++ks) {              // W_hh * h_{t-1}
        bf16x8 a = *(const bf16x8*)&w_s[wrow + 512 + ks*32 + koff];
        bf16x8 bb = *(const bf16x8*)&in_s[brow + ks*32 + koff];
        acc = __builtin_amdgcn_mfma_f32_16x16x32_bf16(a, bb, acc, 0, 0, 0);
      }
    }

    // D layout: row = lg*4 + reg (gate-local h-dim), col = lr (batch)
    #pragma unroll
    for (int j2 = 0; j2 < 4; ++j2)
      g_s[(wv*16 + lg*4 + j2)*16 + lr] = acc[j2];
    __syncthreads();

    // elementwise cell update: one (hd, b) pair per thread
    float gi = g_s[(  0 + hd)*16 + b_loc] + b_i;
    float gf = g_s[( 16 + hd)*16 + b_loc] + b_f;
    float gg = g_s[( 32 + hd)*16 + b_loc] + b_g;
    float go = g_s[( 48 + hd)*16 + b_loc] + b_o;
    float si = 1.f/(1.f + __expf(-gi));
    float sf = 1.f/(1.f + __expf(-gf));
    float tg = tanhf(gg);
    float so = 1.f/(1.f + __expf(-go));
    c_reg = sf*c_reg + si*tg;
    float hv = so * tanhf(c_reg);

    // h store: pack 2 bf16 -> u32, relaxed agent-scope store (write-through,
    // no buffer_wbl2). Partner thread tid^1 holds hd^1.
    unsigned int hb = (unsigned int)f2bf(hv);
    unsigned int other = __shfl_xor(hb, 1);
    if ((tid & 1) == 0) {
      unsigned int packed = hb | (other << 16);
      __hip_atomic_store(
          (unsigned int*)&hout[((size_t)t*64 + bs*16 + b_loc)*512 + gs*16 + hd],
          packed, __ATOMIC_RELAXED, __HIP_MEMORY_SCOPE_AGENT);
    }

    // __syncthreads drains vmcnt(0) for every thread -> all h stores are at the
    // coherent point before the flag store below (hand-rolled release).
    __syncthreads();
    if (tid == 0)
      __hip_atomic_store(&flg_self[gs], (unsigned)(t + 1),
                         __ATOMIC_RELAXED, __HIP_MEMORY_SCOPE_AGENT);
  }
}

// ---------------- FC: out[b][t][v] = h1[t*64+b] . wfc[v] + bfc[v] ----------------
__global__ __launch_bounds__(256, 2) void fc_gemm(
    const ushort_t* __restrict__ h1,    // [12544][512] bf16
    const ushort_t* __restrict__ wfc,   // [5120][512] bf16 (padded)
    const float* __restrict__ bfc,      // [5000]
    float* __restrict__ out)            // [64][196][5000]
{
  __shared__ ushort_t As[128*32];
  __shared__ ushort_t Bs[128*32];
  const int tid = threadIdx.x;
  const int wvid = tid >> 6, lane = tid & 63;
  const int lr = lane & 15, lg = lane >> 4;
  const int wr = wvid >> 1, wc = wvid & 1;
  const int m0 = blockIdx.x * 128, n0 = blockIdx.y * 128;

  f32x4 acc[4][4];
  #pragma unroll
  for (int i = 0; i < 4; ++i)
    #pragma unroll
    for (int j = 0; j < 4; ++j)
      acc[i][j] = (f32x4){0.f, 0.f, 0.f, 0.f};

  for (int kt = 0; kt < 16; ++kt) {
    #pragma unroll
    for (int c = 0; c < 2; ++c) {
      int chb = wvid*128 + c*64;
      int ch = chb + lane;
      int m = ch >> 2, kh = ch & 3;
      const ushort_t* ga = h1  + (size_t)(m0 + m)*512 + kt*32 + kh*8;
      __builtin_amdgcn_global_load_lds(
          (const __attribute__((address_space(1))) void*)ga,
          (__attribute__((address_space(3))) void*)&As[chb*8], 16, 0, 0);
      const ushort_t* gb = wfc + (size_t)(n0 + m)*512 + kt*32 + kh*8;
      __builtin_amdgcn_global_load_lds(
          (const __attribute__((address_space(1))) void*)gb,
          (__attribute__((address_space(3))) void*)&Bs[chb*8], 16, 0, 0);
    }
    asm volatile("s_waitcnt vmcnt(0)" ::: "memory");
    __syncthreads();

    bf16x8 af[4], bf_[4];
    #pragma unroll
    for (int i = 0; i < 4; ++i)
      af[i] = *(const bf16x8*)&As[(wr*64 + i*16 + lr)*32 + lg*8];
    #pragma unroll
    for (int j = 0; j < 4; ++j)
      bf_[j] = *(const bf16x8*)&Bs[(wc*64 + j*16 + lr)*32 + lg*8];
    #pragma unroll
    for (int i = 0; i < 4; ++i)
      #pragma unroll
      for (int j = 0; j < 4; ++j)
        acc[i][j] = __builtin_amdgcn_mfma_f32_16x16x32_bf16(af[i], bf_[j], acc[i][j], 0, 0, 0);
    __syncthreads();
  }

  #pragma unroll
  for (int j = 0; j < 4; ++j) {
    int coln = n0 + wc*64 + j*16 + lr;
    if (coln >= 5000) continue;
    float bb = bfc[coln];
    #pragma unroll
    for (int i = 0; i < 4; ++i) {
      #pragma unroll
      for (int jj = 0; jj < 4; ++jj) {
        int rowm = m0 + wr*64 + i*16 + lg*4 + jj;
        int tt = rowm >> 6, b2 = rowm & 63;
        out[(size_t)b2*980000 + (size_t)tt*5000 + coln] = acc[i][j][jj] + bb;
      }
    }
  }
}

extern "C" void kernel_launch(void* const* d_in, const int* in_sizes, int n_in,
                              void* d_out, int out_size, void* d_ws, size_t ws_size,
                              hipStream_t stream) {
  const float* x    = (const float*)d_in[0];
  const float* Wih0 = (const float*)d_in[1];
  const float* Whh0 = (const float*)d_in[2];
  const float* bih0 = (const float*)d_in[3];
  const float* bhh0 = (const float*)d_in[4];
  const float* Wih1 = (const float*)d_in[5];
  const float* Whh1 = (const float*)d_in[6];
  const float* bih1 = (const float*)d_in[7];
  const float* bhh1 = (const float*)d_in[8];
  const float* Wfc  = (const float*)d_in[9];
  const float* bfc  = (const float*)d_in[10];

  char* ws = (char*)d_ws;
  ushort_t* wpack = (ushort_t*)(ws + O_WPACK);
  ushort_t* wfcp  = (ushort_t*)(ws + O_WFC);
  float*    bias  = (float*)(ws + O_BIAS);
  ushort_t* seqT  = (ushort_t*)(ws + O_SEQT);
  ushort_t* h_all = (ushort_t*)(ws + O_H);
  unsigned int* flags = (unsigned int*)(ws + O_FLG);

  hipFuncSetAttribute((const void*)lstm_scan,
                      hipFuncAttributeMaxDynamicSharedMemorySize, SCAN_LDS_BYTES);

  prep_pack<<<4096, 256, 0, stream>>>(Wih0, Whh0, bih0, bhh0,
                                      Wih1, Whh1, bih1, bhh1,
                                      Wfc, wpack, wfcp, bias, flags);
  prep_seq<<<512, 256, 0, stream>>>(x, seqT);
  lstm_scan<<<256, 256, SCAN_LDS_BYTES, stream>>>(wpack, bias, seqT, h_all, flags);
  dim3 fcg(98, 40);
  fc_gemm<<<fcg, 256, 0, stream>>>(h_all + (size_t)196*64*512, wfcp, bfc,
                                   (float*)d_out);
}